// Round 3
// baseline (2060.260 us; speedup 1.0000x reference)
//
#include <hip/hip_runtime.h>
#include <cstdint>

#define Eexp 8
#define Bb   16384
#define Dd   512
#define Hh   512
#define Zz   64

typedef _Float16 f16x8 __attribute__((ext_vector_type(8)));
typedef _Float16 f16x4 __attribute__((ext_vector_type(4)));
typedef float    f32x4 __attribute__((ext_vector_type(4)));

// per-expert transposed-split weight region (elements), fixed layout
#define PEREXP     1671168
#define OFF_ENCIN  0
#define OFF_HID0   262144
#define OFF_HID1   524288
#define OFF_MU     786432
#define OFF_LV     819200
#define OFF_DECIN  851968
#define OFF_DHID0  884736
#define OFF_DHID1  1146880
#define OFF_DECOUT 1409024
#define WT_ELEMS   (8 * (size_t)PEREXP)

#define GLL16(g, l) __builtin_amdgcn_global_load_lds( \
    (const __attribute__((address_space(1))) void*)(g), \
    (__attribute__((address_space(3))) void*)(l), 16, 0, 0)

// ---------------------------------------------------------------------------
// Weight transpose + f16 hi/lo split:  src[K,N] fp32 -> dst[N,K] f16 (hi,lo)
// ---------------------------------------------------------------------------
__global__ __launch_bounds__(256)
void tsplit(const float* __restrict__ src, _Float16* __restrict__ dH,
            _Float16* __restrict__ dL, int K, int N, long sStride, long dStride)
{
    __shared__ float t[64][65];
    const int e  = blockIdx.z;
    const int n0 = blockIdx.x * 64, k0 = blockIdx.y * 64;
    const float* S = src + (size_t)e * sStride;
    const int tid = threadIdx.x;
    const int rr = tid >> 4, cc = (tid & 15) * 4;
    #pragma unroll
    for (int p = 0; p < 4; ++p) {
        const float4 v = *reinterpret_cast<const float4*>(
            &S[(size_t)(k0 + rr + p * 16) * N + n0 + cc]);
        t[rr + p * 16][cc + 0] = v.x; t[rr + p * 16][cc + 1] = v.y;
        t[rr + p * 16][cc + 2] = v.z; t[rr + p * 16][cc + 3] = v.w;
    }
    __syncthreads();
    _Float16* DH = dH + (size_t)e * dStride;
    _Float16* DL = dL + (size_t)e * dStride;
    #pragma unroll
    for (int p = 0; p < 4; ++p) {
        const int no = rr + p * 16;
        const float a = t[cc + 0][no], b = t[cc + 1][no];
        const float c = t[cc + 2][no], d = t[cc + 3][no];
        const _Float16 ha = (_Float16)a, hb = (_Float16)b;
        const _Float16 hc = (_Float16)c, hd = (_Float16)d;
        f16x4 hv = {ha, hb, hc, hd};
        f16x4 lv = {(_Float16)(a - (float)ha), (_Float16)(b - (float)hb),
                    (_Float16)(c - (float)hc), (_Float16)(d - (float)hd)};
        *reinterpret_cast<f16x4*>(&DH[(size_t)(n0 + no) * K + k0 + cc]) = hv;
        *reinterpret_cast<f16x4*>(&DL[(size_t)(n0 + no) * K + k0 + cc]) = lv;
    }
}

// fp32 -> f16 hi/lo planes (for x), float4-vectorized
__global__ __launch_bounds__(256)
void xsplit(const float4* __restrict__ src, f16x4* __restrict__ dh,
            f16x4* __restrict__ dl)
{
    const int i = blockIdx.x * 256 + threadIdx.x;
    const float4 v = src[i];
    const _Float16 h0 = (_Float16)v.x, h1 = (_Float16)v.y;
    const _Float16 h2 = (_Float16)v.z, h3 = (_Float16)v.w;
    f16x4 hv = {h0, h1, h2, h3};
    f16x4 lv = {(_Float16)(v.x - (float)h0), (_Float16)(v.y - (float)h1),
                (_Float16)(v.z - (float)h2), (_Float16)(v.w - (float)h3)};
    dh[i] = hv; dl[i] = lv;
}

// ---------------------------------------------------------------------------
// Split-f16 MFMA GEMM, both operands staged via global_load_lds (pre-swizzled
// per-lane source, linear LDS dest). A planes [M,Ka] f16, W planes [N,Ka] f16.
// BM=128, BK=32, 256 thr = 4 waves (2x2). XOR slot swizzle s ^= (r>>1)&3.
// MODE 0: relu + split-f16 out (two planes)   (hidden layers)
// MODE 1: fp32 out, no relu                   (dec_out)
// MODE 2: dual fp32 out, grid.y-half selects W/bias/C set (mu & lv fused)
// 1-D grid with bijective XCD swizzle, col-block-fastest logical order so
// each XCD reuses its A row-panel across all column blocks in its L2.
// ---------------------------------------------------------------------------
template<int BN, int MODE>
__global__ __launch_bounds__(256, 2)
void gemm_sp(const _Float16* __restrict__ Ah, const _Float16* __restrict__ Al,
             const _Float16* __restrict__ Wh0, const _Float16* __restrict__ Wl0,
             const float* __restrict__ bias0,
             float* __restrict__ Cf0, _Float16* __restrict__ Ch0,
             _Float16* __restrict__ Cl0,
             const _Float16* __restrict__ Wh1, const _Float16* __restrict__ Wl1,
             const float* __restrict__ bias1, float* __restrict__ Cf1,
             int Ka, int Nout)
{
    constexpr int BM = 128, BK = 32;
    constexpr int WN = BN / 2;        // wave n-extent
    constexpr int NF = WN / 16;
    constexpr int CPW = BN / 64;      // W chunks per wave per plane
    __shared__ __align__(16) _Float16 sAh[BM * BK], sAl[BM * BK];
    __shared__ __align__(16) _Float16 sWh[BN * BK], sWl[BN * BK];

    // ---- XCD-aware bijective remap (gridDim.x % 8 == 0 for all our grids)
    const int nY = (MODE == 2) ? 2 : (Nout / BN);
    int wg = blockIdx.x;
    wg = (wg & 7) * (gridDim.x >> 3) + (wg >> 3);
    const int bx = wg / nY;
    const int by = wg % nY;

    const _Float16* WhP = Wh0; const _Float16* WlP = Wl0;
    const float* biasP = bias0; float* CfP = Cf0;
    if (MODE == 2 && by == 1) { WhP = Wh1; WlP = Wl1; biasP = bias1; CfP = Cf1; }

    const int tid  = threadIdx.x;
    const int lane = tid & 63;
    const int wid  = tid >> 6;
    const int wr = wid >> 1, wc = wid & 1;
    const int row0 = bx * BM;
    const int col0 = (MODE == 2) ? 0 : by * BN;

    f32x4 acc[4][NF];
    #pragma unroll
    for (int i = 0; i < 4; ++i)
        #pragma unroll
        for (int j = 0; j < NF; ++j) acc[i][j] = {0.f, 0.f, 0.f, 0.f};

    for (int k0 = 0; k0 < Ka; k0 += BK) {
        __syncthreads();
        // ---- A tiles: 8 chunks per plane (16 rows x 32 f16 each)
        #pragma unroll
        for (int p = 0; p < 2; ++p) {
            const int q  = wid * 2 + p;
            const int rl = q * 16 + (lane >> 2);
            const int c  = (lane & 3) ^ ((rl >> 1) & 3);
            const size_t gi = (size_t)(row0 + rl) * Ka + k0 + c * 8;
            GLL16(Ah + gi, &sAh[q * 512]);
            GLL16(Al + gi, &sAl[q * 512]);
        }
        // ---- W tiles: BN/16 chunks per plane
        #pragma unroll
        for (int p = 0; p < CPW; ++p) {
            const int q  = wid * CPW + p;
            const int rl = q * 16 + (lane >> 2);
            const int c  = (lane & 3) ^ ((rl >> 1) & 3);
            const size_t gi = (size_t)(col0 + rl) * Ka + k0 + c * 8;
            GLL16(WhP + gi, &sWh[q * 512]);
            GLL16(WlP + gi, &sWl[q * 512]);
        }
        __syncthreads();
        // ---- fragments + 3-term MFMA
        f16x8 fah[4], fal[4], fwh[NF], fwl[NF];
        #pragma unroll
        for (int mf = 0; mf < 4; ++mf) {
            const int r = wr * 64 + mf * 16 + (lane & 15);
            const int c = (lane >> 4) ^ ((r >> 1) & 3);
            const int idx = r * 32 + c * 8;
            fah[mf] = *reinterpret_cast<f16x8*>(&sAh[idx]);
            fal[mf] = *reinterpret_cast<f16x8*>(&sAl[idx]);
        }
        #pragma unroll
        for (int nf = 0; nf < NF; ++nf) {
            const int r = wc * WN + nf * 16 + (lane & 15);
            const int c = (lane >> 4) ^ ((r >> 1) & 3);
            const int idx = r * 32 + c * 8;
            fwh[nf] = *reinterpret_cast<f16x8*>(&sWh[idx]);
            fwl[nf] = *reinterpret_cast<f16x8*>(&sWl[idx]);
        }
        #pragma unroll
        for (int mf = 0; mf < 4; ++mf)
            #pragma unroll
            for (int nf = 0; nf < NF; ++nf) {
                acc[mf][nf] = __builtin_amdgcn_mfma_f32_16x16x32_f16(
                    fah[mf], fwh[nf], acc[mf][nf], 0, 0, 0);
                acc[mf][nf] = __builtin_amdgcn_mfma_f32_16x16x32_f16(
                    fah[mf], fwl[nf], acc[mf][nf], 0, 0, 0);
                acc[mf][nf] = __builtin_amdgcn_mfma_f32_16x16x32_f16(
                    fal[mf], fwh[nf], acc[mf][nf], 0, 0, 0);
            }
    }

    // ---- epilogue
    #pragma unroll
    for (int nf = 0; nf < NF; ++nf) {
        const int col = col0 + wc * WN + nf * 16 + (lane & 15);
        const float bv = biasP[col];
        #pragma unroll
        for (int mf = 0; mf < 4; ++mf)
            #pragma unroll
            for (int j = 0; j < 4; ++j) {
                const int rowg = row0 + wr * 64 + mf * 16 + (lane >> 4) * 4 + j;
                float v = acc[mf][nf][j] + bv;
                if (MODE == 0) {
                    v = fmaxf(v, 0.f);
                    const _Float16 h = (_Float16)v;
                    const _Float16 l = (_Float16)(v - (float)h);
                    Ch0[(size_t)rowg * Nout + col] = h;
                    Cl0[(size_t)rowg * Nout + col] = l;
                } else {
                    CfP[(size_t)rowg * Nout + col] = v;
                }
            }
    }
}

// z = mu + exp(0.5*logvar)*eps -> split f16 planes
__global__ __launch_bounds__(256)
void z_kernel(const float4* __restrict__ mu, const float4* __restrict__ lv,
              const float4* __restrict__ eps, f16x4* __restrict__ zh,
              f16x4* __restrict__ zl)
{
    const int i = blockIdx.x * 256 + threadIdx.x;
    const float4 m = mu[i], l = lv[i], e = eps[i];
    float4 r;
    r.x = m.x + expf(0.5f * l.x) * e.x;
    r.y = m.y + expf(0.5f * l.y) * e.y;
    r.z = m.z + expf(0.5f * l.z) * e.z;
    r.w = m.w + expf(0.5f * l.w) * e.w;
    const _Float16 h0 = (_Float16)r.x, h1 = (_Float16)r.y;
    const _Float16 h2 = (_Float16)r.z, h3 = (_Float16)r.w;
    f16x4 hv = {h0, h1, h2, h3};
    f16x4 lvv = {(_Float16)(r.x - (float)h0), (_Float16)(r.y - (float)h1),
                 (_Float16)(r.z - (float)h2), (_Float16)(r.w - (float)h3)};
    zh[i] = hv; zl[i] = lvv;
}

__global__ __launch_bounds__(256)
void recon_kernel(const float* __restrict__ xhat, const float* __restrict__ x,
                  float* __restrict__ recon)
{
    const int wave = threadIdx.x >> 6;
    const int lane = threadIdx.x & 63;
    const int row  = blockIdx.x * 4 + wave;
    const float4* xh = reinterpret_cast<const float4*>(&xhat[(size_t)row * Dd]);
    const float4* xx = reinterpret_cast<const float4*>(&x[(size_t)row * Dd]);
    float s = 0.f;
    #pragma unroll
    for (int it = 0; it < 2; ++it) {
        const float4 a = xh[lane + it * 64];
        const float4 b = xx[lane + it * 64];
        float d;
        d = a.x - b.x; s = fmaf(d, d, s);
        d = a.y - b.y; s = fmaf(d, d, s);
        d = a.z - b.z; s = fmaf(d, d, s);
        d = a.w - b.w; s = fmaf(d, d, s);
    }
    #pragma unroll
    for (int off = 32; off > 0; off >>= 1) s += __shfl_down(s, off);
    if (lane == 0) recon[row] = s * (1.0f / 512.0f);
}

__global__ __launch_bounds__(256)
void select_kernel(const float* __restrict__ recon, float* __restrict__ best,
                   const float* __restrict__ mu_e, const float* __restrict__ lv_e,
                   const float* __restrict__ xhat,
                   float* __restrict__ out_mu, float* __restrict__ out_lv,
                   float* __restrict__ out_xh, int isFirst)
{
    const int wave = threadIdx.x >> 6;
    const int lane = threadIdx.x & 63;
    const int row  = blockIdx.x * 4 + wave;
    const float r  = recon[row];
    const bool cond = isFirst || (r < best[row]);
    if (cond) {
        if (lane == 0) best[row] = r;
        out_mu[(size_t)row * Zz + lane] = mu_e[(size_t)row * Zz + lane];
        out_lv[(size_t)row * Zz + lane] = lv_e[(size_t)row * Zz + lane];
        const float4* src = reinterpret_cast<const float4*>(&xhat[(size_t)row * Dd]);
        float4*       dst = reinterpret_cast<float4*>(&out_xh[(size_t)row * Dd]);
        dst[lane]      = src[lane];
        dst[lane + 64] = src[lane + 64];
    }
}

extern "C" void kernel_launch(void* const* d_in, const int* in_sizes, int n_in,
                              void* d_out, int out_size, void* d_ws, size_t ws_size,
                              hipStream_t stream)
{
    const float* x         = (const float*)d_in[0];
    const float* eps       = (const float*)d_in[1];
    const float* enc_in_w  = (const float*)d_in[2];
    const float* enc_in_b  = (const float*)d_in[3];
    const float* enc_hid_w = (const float*)d_in[4];
    const float* enc_hid_b = (const float*)d_in[5];
    const float* mu_w      = (const float*)d_in[6];
    const float* mu_b      = (const float*)d_in[7];
    const float* lv_w      = (const float*)d_in[8];
    const float* lv_b      = (const float*)d_in[9];
    const float* dec_in_w  = (const float*)d_in[10];
    const float* dec_in_b  = (const float*)d_in[11];
    const float* dec_hid_w = (const float*)d_in[12];
    const float* dec_hid_b = (const float*)d_in[13];
    const float* dec_out_w = (const float*)d_in[14];
    const float* dec_out_b = (const float*)d_in[15];

    const size_t BD = (size_t)Bb * 512;   // activation plane elems
    const size_t BZ = (size_t)Bb * 64;

    _Float16* wtH = (_Float16*)d_ws;
    _Float16* wtL = wtH + WT_ELEMS;
    _Float16* xh  = wtL + WT_ELEMS;
    _Float16* xl  = xh + BD;
    _Float16* aH  = xl + BD;
    _Float16* aL  = aH + BD;
    _Float16* bH  = aL + BD;
    _Float16* bL  = bH + BD;
    _Float16* zh  = bL + BD;
    _Float16* zl  = zh + BZ;
    float* fbase  = (float*)(zl + BZ);
    float* xhat   = fbase;                 // [B,512] fp32
    float* mu_e   = xhat + BD;             // [B,64]
    float* lv_e   = mu_e + BZ;
    float* rec    = lv_e + BZ;
    float* best   = rec + Bb;

    float* out_mu = (float*)d_out;
    float* out_lv = out_mu + (size_t)Bb * Zz;
    float* out_xh = out_lv + (size_t)Bb * Zz;

    const dim3 blk(256);

    // ---- one-time weight transpose+split and x split ----
    tsplit<<<dim3(8, 8, 8), blk, 0, stream>>>(enc_in_w,           wtH + OFF_ENCIN,  wtL + OFF_ENCIN,  512, 512, 262144, PEREXP);
    tsplit<<<dim3(8, 8, 8), blk, 0, stream>>>(enc_hid_w,          wtH + OFF_HID0,   wtL + OFF_HID0,   512, 512, 524288, PEREXP);
    tsplit<<<dim3(8, 8, 8), blk, 0, stream>>>(enc_hid_w + 262144, wtH + OFF_HID1,   wtL + OFF_HID1,   512, 512, 524288, PEREXP);
    tsplit<<<dim3(1, 8, 8), blk, 0, stream>>>(mu_w,               wtH + OFF_MU,     wtL + OFF_MU,     512,  64,  32768, PEREXP);
    tsplit<<<dim3(1, 8, 8), blk, 0, stream>>>(lv_w,               wtH + OFF_LV,     wtL + OFF_LV,     512,  64,  32768, PEREXP);
    tsplit<<<dim3(8, 1, 8), blk, 0, stream>>>(dec_in_w,           wtH + OFF_DECIN,  wtL + OFF_DECIN,   64, 512,  32768, PEREXP);
    tsplit<<<dim3(8, 8, 8), blk, 0, stream>>>(dec_hid_w,          wtH + OFF_DHID0,  wtL + OFF_DHID0,  512, 512, 524288, PEREXP);
    tsplit<<<dim3(8, 8, 8), blk, 0, stream>>>(dec_hid_w + 262144, wtH + OFF_DHID1,  wtL + OFF_DHID1,  512, 512, 524288, PEREXP);
    tsplit<<<dim3(8, 8, 8), blk, 0, stream>>>(dec_out_w,          wtH + OFF_DECOUT, wtL + OFF_DECOUT, 512, 512, 262144, PEREXP);
    xsplit<<<dim3(BD / 4 / 256), blk, 0, stream>>>(
        (const float4*)x, (f16x4*)xh, (f16x4*)xl);

    const dim3 gBig(512);    // 128 row-blocks x 4 col-blocks
    const dim3 gDual(256);   // 128 row-blocks x 2 (mu,lv)
    const dim3 gRow(Bb / 4);
    const dim3 gZ(BZ / 4 / 256);

    for (int e = 0; e < Eexp; ++e) {
        const size_t wo = (size_t)e * PEREXP;
        // encoder
        gemm_sp<128, 0><<<gBig, blk, 0, stream>>>(
            xh, xl, wtH + wo + OFF_ENCIN, wtL + wo + OFF_ENCIN,
            enc_in_b + (size_t)e * Hh, nullptr, aH, aL,
            nullptr, nullptr, nullptr, nullptr, Dd, Hh);
        gemm_sp<128, 0><<<gBig, blk, 0, stream>>>(
            aH, aL, wtH + wo + OFF_HID0, wtL + wo + OFF_HID0,
            enc_hid_b + ((size_t)e * 2 + 0) * Hh, nullptr, bH, bL,
            nullptr, nullptr, nullptr, nullptr, Hh, Hh);
        gemm_sp<128, 0><<<gBig, blk, 0, stream>>>(
            bH, bL, wtH + wo + OFF_HID1, wtL + wo + OFF_HID1,
            enc_hid_b + ((size_t)e * 2 + 1) * Hh, nullptr, aH, aL,
            nullptr, nullptr, nullptr, nullptr, Hh, Hh);
        // heads (dual)
        gemm_sp<64, 2><<<gDual, blk, 0, stream>>>(
            aH, aL, wtH + wo + OFF_MU, wtL + wo + OFF_MU,
            mu_b + (size_t)e * Zz, mu_e, nullptr, nullptr,
            wtH + wo + OFF_LV, wtL + wo + OFF_LV,
            lv_b + (size_t)e * Zz, lv_e, Hh, Zz);
        // reparameterize -> split z
        z_kernel<<<gZ, blk, 0, stream>>>(
            (const float4*)mu_e, (const float4*)lv_e, (const float4*)eps,
            (f16x4*)zh, (f16x4*)zl);
        // decoder
        gemm_sp<128, 0><<<gBig, blk, 0, stream>>>(
            zh, zl, wtH + wo + OFF_DECIN, wtL + wo + OFF_DECIN,
            dec_in_b + (size_t)e * Hh, nullptr, bH, bL,
            nullptr, nullptr, nullptr, nullptr, Zz, Hh);
        gemm_sp<128, 0><<<gBig, blk, 0, stream>>>(
            bH, bL, wtH + wo + OFF_DHID0, wtL + wo + OFF_DHID0,
            dec_hid_b + ((size_t)e * 2 + 0) * Hh, nullptr, aH, aL,
            nullptr, nullptr, nullptr, nullptr, Hh, Hh);
        gemm_sp<128, 0><<<gBig, blk, 0, stream>>>(
            aH, aL, wtH + wo + OFF_DHID1, wtL + wo + OFF_DHID1,
            dec_hid_b + ((size_t)e * 2 + 1) * Hh, nullptr, bH, bL,
            nullptr, nullptr, nullptr, nullptr, Hh, Hh);
        gemm_sp<128, 1><<<gBig, blk, 0, stream>>>(
            bH, bL, wtH + wo + OFF_DECOUT, wtL + wo + OFF_DECOUT,
            dec_out_b + (size_t)e * Dd, xhat, nullptr, nullptr,
            nullptr, nullptr, nullptr, nullptr, Hh, Dd);
        // recon + running-min gather
        recon_kernel<<<gRow, blk, 0, stream>>>(xhat, x, rec);
        select_kernel<<<gRow, blk, 0, stream>>>(
            rec, best, mu_e, lv_e, xhat, out_mu, out_lv, out_xh, e == 0 ? 1 : 0);
    }
}